// Round 1
// 3586.061 us; speedup vs baseline: 1.6296x; 1.6296x over previous
//
#include <hip/hip_runtime.h>
#include <hip/hip_bf16.h>
#include <cstdint>
#include <cstddef>

// ---------------- problem constants ----------------
#define BATCH    4
#define SEQ      1024
#define DMODEL   1152
#define NHEADS   16
#define HEADDIM  72
#define FFDIM    4304
#define NLAYERS  6
#define PATCHIN  588
#define LN_EPS   1e-6f

typedef float f32x4 __attribute__((ext_vector_type(4)));
typedef __bf16 bf16x8 __attribute__((ext_vector_type(8)));
typedef short s16x8 __attribute__((ext_vector_type(8)));

__device__ __forceinline__ unsigned short f2bf(float f) {
  unsigned u = __builtin_bit_cast(unsigned, f);
  u = (u + 0x7fffu + ((u >> 16) & 1u)) >> 16;
  return (unsigned short)u;
}
__device__ __forceinline__ float bfu2f(unsigned short u) {
  return __builtin_bit_cast(float, (unsigned)u << 16);
}
__device__ __forceinline__ float gelu_tanh(float x) {
  const float c0 = 0.7978845608028654f, c1 = 0.044715f;
  return 0.5f * x * (1.0f + tanhf(c0 * (x + c1 * x * x * x)));
}
__device__ __forceinline__ void gload16(const unsigned short* g, unsigned short* l) {
  __builtin_amdgcn_global_load_lds(
      (__attribute__((address_space(1))) void*)g,
      (__attribute__((address_space(3))) void*)l, 16, 0, 0);
}

// ---------------- bf16 MFMA GEMM, B^T weights, global_load_lds staging ------
// C[M,N] = epi(A[M,K] @ BT[N,K]^T + bias). A,BT bf16 row-major, K%32==0.
// mode: 0=+bias, 1=+bias+Rres(f32), 2=gelu(+bias). outbf: 1 -> bf16 C.
__global__ __launch_bounds__(256) void gemm_bt(
    const unsigned short* __restrict__ A, const unsigned short* __restrict__ BT,
    const float* __restrict__ bias, const float* __restrict__ Rres,
    void* __restrict__ Cout, int M, int N, int K, int ldc, int Nzero,
    int mode, int outbf)
{
  __shared__ __align__(16) unsigned short As[128 * 32];  // 8 KB, unpadded
  __shared__ __align__(16) unsigned short Bs[128 * 32];
  const int tid = threadIdx.x;
  const int wave = tid >> 6, lane = tid & 63;
  const int lr = lane & 15, lq = lane >> 4;
  const int m0 = blockIdx.y * 128, n0 = blockIdx.x * 128;
  const int wm = (wave & 1) * 64, wn = (wave >> 1) * 64;

  // staging map: slot s in {tid, tid+256}; row = s>>2, kchunk = s&3 (8 bf16).
  const int rowA = tid >> 2, kc = tid & 3;
  const unsigned short* gA0 = A + (size_t)(m0 + rowA) * K + kc * 8;
  const unsigned short* gA1 = gA0 + (size_t)64 * K;
  const int rB0 = min(n0 + rowA, N - 1);        // clamp tail (discarded cols)
  const int rB1 = min(n0 + rowA + 64, N - 1);
  const unsigned short* gB0 = BT + (size_t)rB0 * K + kc * 8;
  const unsigned short* gB1 = BT + (size_t)rB1 * K + kc * 8;
  unsigned short* lA0 = &As[tid * 8];
  unsigned short* lA1 = &As[(tid + 256) * 8];
  unsigned short* lB0 = &Bs[tid * 8];
  unsigned short* lB1 = &Bs[(tid + 256) * 8];

  f32x4 acc[4][4];
#pragma unroll
  for (int i = 0; i < 4; ++i)
#pragma unroll
    for (int j = 0; j < 4; ++j) acc[i][j] = (f32x4)(0.0f);

  for (int k0 = 0; k0 < K; k0 += 32) {
    gload16(gA0 + k0, lA0);
    gload16(gA1 + k0, lA1);
    gload16(gB0 + k0, lB0);
    gload16(gB1 + k0, lB1);
    __syncthreads();
    s16x8 af[4], bfr[4];
#pragma unroll
    for (int mi = 0; mi < 4; ++mi)
      af[mi] = *(const s16x8*)&As[(wm + mi * 16 + lr) * 32 + lq * 8];
#pragma unroll
    for (int ni = 0; ni < 4; ++ni)
      bfr[ni] = *(const s16x8*)&Bs[(wn + ni * 16 + lr) * 32 + lq * 8];
#pragma unroll
    for (int mi = 0; mi < 4; ++mi)
#pragma unroll
      for (int ni = 0; ni < 4; ++ni)
        acc[mi][ni] = __builtin_amdgcn_mfma_f32_16x16x32_bf16(
            __builtin_bit_cast(bf16x8, af[mi]),
            __builtin_bit_cast(bf16x8, bfr[ni]), acc[mi][ni], 0, 0, 0);
    __syncthreads();
  }
  // epilogue: D[row=(lane>>4)*4+r][col=lane&15]  (verified layout)
  unsigned short* cb = (unsigned short*)Cout;
  float* cf = (float*)Cout;
#pragma unroll
  for (int ni = 0; ni < 4; ++ni) {
    const int col = n0 + wn + ni * 16 + lr;
    if (col < N) {
      const float bv = bias[col];
#pragma unroll
      for (int mi = 0; mi < 4; ++mi)
#pragma unroll
        for (int r = 0; r < 4; ++r) {
          const int row = m0 + wm + mi * 16 + lq * 4 + r;
          float v = acc[mi][ni][r] + bv;
          if (mode == 1) v += Rres[(size_t)row * ldc + col];
          else if (mode == 2) v = gelu_tanh(v);
          if (outbf) cb[(size_t)row * ldc + col] = f2bf(v);
          else cf[(size_t)row * ldc + col] = v;
        }
    } else if (col < Nzero) {   // zero-fill K-padding columns (bf16 out only)
#pragma unroll
      for (int mi = 0; mi < 4; ++mi)
#pragma unroll
        for (int r = 0; r < 4; ++r) {
          const int row = m0 + wm + mi * 16 + lq * 4 + r;
          cb[(size_t)row * ldc + col] = 0;
        }
    }
  }
}

// ---------------- weight transpose + fp32->bf16 convert ----------------
// W[K][N] f32  ->  WT[N][KP] bf16, zero-padded for k in [K,KP). KP%32==0.
__global__ __launch_bounds__(256) void transpose_cvt(
    const float* __restrict__ W, unsigned short* __restrict__ WT,
    int K, int N, int KP)
{
  __shared__ float t[32][33];
  const int n0 = blockIdx.x * 32, k0 = blockIdx.y * 32;
  const int tx = threadIdx.x, ty = threadIdx.y;
#pragma unroll
  for (int i = 0; i < 32; i += 8) {
    const int k = k0 + ty + i, n = n0 + tx;
    t[ty + i][tx] = (k < K && n < N) ? W[(size_t)k * N + n] : 0.f;
  }
  __syncthreads();
#pragma unroll
  for (int i = 0; i < 32; i += 8) {
    const int n = n0 + ty + i, k = k0 + tx;
    if (n < N) WT[(size_t)n * KP + k] = f2bf(t[tx][ty + i]);
  }
}

// ---------------- pixel f32 -> bf16 with K-pad 588->608 ----------------
__global__ __launch_bounds__(256) void cvt_pixel(
    const float* __restrict__ P, unsigned short* __restrict__ Pb)
{
  const int col = blockIdx.x * 256 + threadIdx.x;
  const int row = blockIdx.y;
  if (col < 608) {
    const float v = (col < PATCHIN) ? P[(size_t)row * PATCHIN + col] : 0.f;
    Pb[(size_t)row * 608 + col] = f2bf(v);
  }
}

__global__ __launch_bounds__(256) void concat3(
    const float* __restrict__ a, const float* __restrict__ b,
    const float* __restrict__ c, float* __restrict__ o, int n)
{
  const int i = blockIdx.x * 256 + threadIdx.x;
  if (i < n) { o[i] = a[i]; o[n + i] = b[i]; o[2 * n + i] = c[i]; }
}

// ---------------- LayerNorm rows of 1152: f32 in, f32/bf16 out ----------
__global__ __launch_bounds__(256) void ln_kernel(
    const float* __restrict__ in, const float* __restrict__ w,
    const float* __restrict__ b, float* __restrict__ of32,
    unsigned short* __restrict__ ob16)
{
  const int row = blockIdx.x, tid = threadIdx.x;
  __shared__ float red[8];
  const float4* x4 = (const float4*)(in + (size_t)row * DMODEL);
  const bool has2 = tid < 32;                 // 288 float4 = 256 + 32
  float4 v0 = x4[tid];
  float4 v1 = has2 ? x4[256 + tid] : make_float4(0.f, 0.f, 0.f, 0.f);
  float s = v0.x + v0.y + v0.z + v0.w + v1.x + v1.y + v1.z + v1.w;
  for (int off = 32; off; off >>= 1) s += __shfl_down(s, off);
  if ((tid & 63) == 0) red[tid >> 6] = s;
  __syncthreads();
  const float mean = (red[0] + red[1] + red[2] + red[3]) * (1.0f / DMODEL);
  float vs = (v0.x - mean) * (v0.x - mean) + (v0.y - mean) * (v0.y - mean)
           + (v0.z - mean) * (v0.z - mean) + (v0.w - mean) * (v0.w - mean);
  if (has2)
    vs += (v1.x - mean) * (v1.x - mean) + (v1.y - mean) * (v1.y - mean)
        + (v1.z - mean) * (v1.z - mean) + (v1.w - mean) * (v1.w - mean);
  for (int off = 32; off; off >>= 1) vs += __shfl_down(vs, off);
  if ((tid & 63) == 0) red[4 + (tid >> 6)] = vs;
  __syncthreads();
  const float var = (red[4] + red[5] + red[6] + red[7]) * (1.0f / DMODEL);
  const float rstd = rsqrtf(var + LN_EPS);
  const float4* w4 = (const float4*)w;
  const float4* b4 = (const float4*)b;
  {
    float4 ww = w4[tid], bb = b4[tid], o;
    o.x = (v0.x - mean) * rstd * ww.x + bb.x;
    o.y = (v0.y - mean) * rstd * ww.y + bb.y;
    o.z = (v0.z - mean) * rstd * ww.z + bb.z;
    o.w = (v0.w - mean) * rstd * ww.w + bb.w;
    if (of32) ((float4*)(of32 + (size_t)row * DMODEL))[tid] = o;
    if (ob16) {
      ushort4 u; u.x = f2bf(o.x); u.y = f2bf(o.y); u.z = f2bf(o.z); u.w = f2bf(o.w);
      ((ushort4*)(ob16 + (size_t)row * DMODEL))[tid] = u;
    }
  }
  if (has2) {
    float4 ww = w4[256 + tid], bb = b4[256 + tid], o;
    o.x = (v1.x - mean) * rstd * ww.x + bb.x;
    o.y = (v1.y - mean) * rstd * ww.y + bb.y;
    o.z = (v1.z - mean) * rstd * ww.z + bb.z;
    o.w = (v1.w - mean) * rstd * ww.w + bb.w;
    if (of32) ((float4*)(of32 + (size_t)row * DMODEL))[256 + tid] = o;
    if (ob16) {
      ushort4 u; u.x = f2bf(o.x); u.y = f2bf(o.y); u.z = f2bf(o.z); u.w = f2bf(o.w);
      ((ushort4*)(ob16 + (size_t)row * DMODEL))[256 + tid] = u;
    }
  }
}

// ---------------- position-embedding bilinear resize + add (f32) --------
__global__ __launch_bounds__(288) void pos_add_kernel(
    const float* __restrict__ pos, const int* __restrict__ ssp,
    float* __restrict__ hbuf)
{
  const int bs = blockIdx.x;
  const int b = bs >> 10, s = bs & (SEQ - 1);
  int hs, wd;
  if (ssp[1] == 0 && ssp[3] == 0) { hs = ssp[b * 4]; wd = ssp[b * 4 + 2]; }
  else { hs = ssp[b * 2]; wd = ssp[b * 2 + 1]; }
  int r = 0, c = 0;
  if (s < hs * wd) { r = s / wd; c = s % wd; }
  const float fy = (r + 0.5f) * (16.0f / hs) - 0.5f;
  const float fx = (c + 0.5f) * (16.0f / wd) - 0.5f;
  const float y0f = floorf(fy), x0f = floorf(fx);
  const float ty = fy - y0f, tx = fx - x0f;
  const int y0 = (int)y0f, x0 = (int)x0f;
  const int y0c = min(max(y0, 0), 15), y1c = min(max(y0 + 1, 0), 15);
  const int x0c = min(max(x0, 0), 15), x1c = min(max(x0 + 1, 0), 15);
  const float w00 = (1.f - ty) * (1.f - tx), w01 = (1.f - ty) * tx;
  const float w10 = ty * (1.f - tx), w11 = ty * tx;
  const float* p00 = pos + (size_t)(y0c * 16 + x0c) * DMODEL;
  const float* p01 = pos + (size_t)(y0c * 16 + x1c) * DMODEL;
  const float* p10 = pos + (size_t)(y1c * 16 + x0c) * DMODEL;
  const float* p11 = pos + (size_t)(y1c * 16 + x1c) * DMODEL;
  float* hrow = hbuf + (size_t)bs * DMODEL;
  const int d0 = threadIdx.x * 4;
#pragma unroll
  for (int i = 0; i < 4; ++i) {
    const int d = d0 + i;
    hrow[d] += w00 * p00[d] + w01 * p01[d] + w10 * p10[d] + w11 * p11[d];
  }
}

// ---------------- MFMA flash attention, bf16 fused-QKV in, bf16 out ------
// grid (SEQ/128, NHEADS, BATCH), 512 threads = 8 waves; wave w owns 16 q-rows.
// Fragment layout mirrors gemm_bt (verified): A row=lane&15, k=(lane>>4)*8;
// C row=(lane>>4)*4+r, col=lane&15.
__global__ __launch_bounds__(512, 4) void attn_kernel(
    const unsigned short* __restrict__ QKV, const float* __restrict__ mask,
    unsigned short* __restrict__ Oa)
{
  // strides chosen so all ds_read_b128 fragment reads hit the 8/bank floor:
  // Qs/Ks stride 96 elems (48 dw = 16 mod 32), VT/Ps stride 72 (36 dw = 4 mod 32)
  __shared__ __align__(16) unsigned short Qs[128][96];   // 24.0 KB, d padded 72->96
  __shared__ __align__(16) unsigned short Ks[64][96];    // 12.0 KB
  __shared__ __align__(16) unsigned short VT[80][72];    // 11.25 KB, V transposed [d][j]
  __shared__ __align__(16) unsigned short Ps[128][72];   // 18.0 KB, P bf16 (cols 0..63 used)
  __shared__ float madd_s[64];
  const int tid = threadIdx.x;
  const int wave = tid >> 6, lane = tid & 63;
  const int lr = lane & 15, lq = lane >> 4;
  const int q0 = blockIdx.x * 128, h = blockIdx.y, b = blockIdx.z;
  const int wq0 = wave * 16;
  const float scale = 0.11785113019775793f;     // 1/sqrt(72)

  // zero pads once: Qs/Ks cols [72,96), VT rows [72,80)
  {
    const s16x8 z = {0, 0, 0, 0, 0, 0, 0, 0};
    for (int idx = tid; idx < 128 * 3; idx += 512) {
      const int row = idx / 3, g = idx % 3;
      *(s16x8*)&Qs[row][72 + g * 8] = z;
    }
    if (tid < 64 * 3) {
      const int row = tid / 3, g = tid % 3;
      *(s16x8*)&Ks[row][72 + g * 8] = z;
    }
    if (tid < 72) {
      const int row = 72 + tid / 9, g = tid % 9;
      *(s16x8*)&VT[row][g * 8] = z;
    }
  }
  // load Q tile once (bf16, 16B per item)
  for (int idx = tid; idx < 128 * 9; idx += 512) {
    const int qi = idx / 9, g = idx % 9;
    *(s16x8*)&Qs[qi][g * 8] = *(const s16x8*)(
        QKV + ((size_t)(b * SEQ + q0 + qi)) * 3456 + h * HEADDIM + g * 8);
  }

  f32x4 acc_o[5];
#pragma unroll
  for (int i = 0; i < 5; ++i) acc_o[i] = (f32x4)(0.0f);
  float m_old[4], lden[4];
#pragma unroll
  for (int r = 0; r < 4; ++r) { m_old[r] = -1e30f; lden[r] = 0.f; }

  for (int kt = 0; kt < SEQ / 64; ++kt) {
    const int k0 = kt * 64;
    __syncthreads();        // prev iter's Ks/VT consumers done (also Q ready)
    for (int idx = tid; idx < 64 * 9; idx += 512) {
      const int j = idx / 9, g = idx % 9;
      const size_t base = ((size_t)(b * SEQ + k0 + j)) * 3456 + h * HEADDIM + g * 8;
      const s16x8 kr = *(const s16x8*)(QKV + base + 1152);
      const s16x8 vr = *(const s16x8*)(QKV + base + 2304);
      *(s16x8*)&Ks[j][g * 8] = kr;
#pragma unroll
      for (int i = 0; i < 8; ++i) VT[g * 8 + i][j] = (unsigned short)vr[i];
    }
    if (tid < 64)
      madd_s[tid] = (1.0f - mask[b * SEQ + k0 + tid]) * -3.4028234663852886e38f;
    __syncthreads();

    // ---- QK^T: S[16 q][64 k] per wave, K-dim 96 (3 chunks) -> 12 MFMAs ----
    f32x4 acc[4];
#pragma unroll
    for (int ni = 0; ni < 4; ++ni) acc[ni] = (f32x4)(0.0f);
    s16x8 aq[3];
#pragma unroll
    for (int c = 0; c < 3; ++c)
      aq[c] = *(const s16x8*)&Qs[wq0 + lr][c * 32 + lq * 8];
#pragma unroll
    for (int ni = 0; ni < 4; ++ni)
#pragma unroll
      for (int c = 0; c < 3; ++c) {
        const s16x8 bk = *(const s16x8*)&Ks[ni * 16 + lr][c * 32 + lq * 8];
        acc[ni] = __builtin_amdgcn_mfma_f32_16x16x32_bf16(
            __builtin_bit_cast(bf16x8, aq[c]), __builtin_bit_cast(bf16x8, bk),
            acc[ni], 0, 0, 0);
      }

    // ---- online softmax: 16-lane group owns rows wq0+lq*4+r, col=lr ----
    float sv[4][4];
#pragma unroll
    for (int ni = 0; ni < 4; ++ni) {
      const float ma = madd_s[ni * 16 + lr];
#pragma unroll
      for (int r = 0; r < 4; ++r) sv[ni][r] = acc[ni][r] * scale + ma;
    }
    float alpha[4];
#pragma unroll
    for (int r = 0; r < 4; ++r) {
      float tm = fmaxf(fmaxf(sv[0][r], sv[1][r]), fmaxf(sv[2][r], sv[3][r]));
      tm = fmaxf(tm, __shfl_xor(tm, 1));
      tm = fmaxf(tm, __shfl_xor(tm, 2));
      tm = fmaxf(tm, __shfl_xor(tm, 4));
      tm = fmaxf(tm, __shfl_xor(tm, 8));
      const float mn = fmaxf(m_old[r], tm);
      alpha[r] = __expf(m_old[r] - mn);
      m_old[r] = mn;
    }
    float lsum[4] = {0.f, 0.f, 0.f, 0.f};
#pragma unroll
    for (int ni = 0; ni < 4; ++ni)
#pragma unroll
      for (int r = 0; r < 4; ++r) {
        const float p = __expf(sv[ni][r] - m_old[r]);
        Ps[wq0 + lq * 4 + r][ni * 16 + lr] = f2bf(p);
        lsum[r] += p;
      }
#pragma unroll
    for (int r = 0; r < 4; ++r) {
      float ls = lsum[r];
      ls += __shfl_xor(ls, 1);
      ls += __shfl_xor(ls, 2);
      ls += __shfl_xor(ls, 4);
      ls += __shfl_xor(ls, 8);
      lden[r] = lden[r] * alpha[r] + ls;
    }

    // ---- PV: O[16 q][80 d] += P[16][64] @ V[64][80], 10 MFMAs ----
    // Ps written/read by the SAME wave -> in-order LDS, no barrier needed.
#pragma unroll
    for (int ni = 0; ni < 5; ++ni)
#pragma unroll
      for (int r = 0; r < 4; ++r) acc_o[ni][r] *= alpha[r];
    s16x8 pa[2];
    pa[0] = *(const s16x8*)&Ps[wq0 + lr][lq * 8];
    pa[1] = *(const s16x8*)&Ps[wq0 + lr][32 + lq * 8];
#pragma unroll
    for (int ni = 0; ni < 5; ++ni)
#pragma unroll
      for (int c = 0; c < 2; ++c) {
        const s16x8 bv = *(const s16x8*)&VT[ni * 16 + lr][c * 32 + lq * 8];
        acc_o[ni] = __builtin_amdgcn_mfma_f32_16x16x32_bf16(
            __builtin_bit_cast(bf16x8, pa[c]), __builtin_bit_cast(bf16x8, bv),
            acc_o[ni], 0, 0, 0);
      }
  }

  // epilogue: O row = q0+wq0+lq*4+r, col = ni*16+lr (d<72)
  float rl[4];
#pragma unroll
  for (int r = 0; r < 4; ++r) rl[r] = 1.0f / lden[r];
#pragma unroll
  for (int ni = 0; ni < 5; ++ni) {
    const int col = ni * 16 + lr;
    if (col < HEADDIM) {
#pragma unroll
      for (int r = 0; r < 4; ++r) {
        const int row = q0 + wq0 + lq * 4 + r;
        Oa[((size_t)(b * SEQ + row)) * DMODEL + h * HEADDIM + col] =
            f2bf(acc_o[ni][r] * rl[r]);
      }
    }
  }
}

// ---------------- head attention-pooling (bf16 K/V) ----------------
__global__ __launch_bounds__(256) void head_attn_kernel(
    const float* __restrict__ hq, const unsigned short* __restrict__ Kb,
    const unsigned short* __restrict__ Vb, const float* __restrict__ mask,
    float* __restrict__ hp)
{
  __shared__ float sc[SEQ];
  __shared__ float red[8];
  __shared__ float qv[HEADDIM];
  __shared__ float opart[3][HEADDIM];
  const int h = blockIdx.x, b = blockIdx.y, tid = threadIdx.x;
  const float scale = 0.11785113019775793f;
  if (tid < HEADDIM) qv[tid] = hq[h * HEADDIM + tid];
  __syncthreads();
  for (int j = tid; j < SEQ; j += 256) {
    const ushort4* kr4 = (const ushort4*)(
        Kb + ((size_t)(b * SEQ + j)) * DMODEL + h * HEADDIM);
    float s = 0.f;
#pragma unroll
    for (int g = 0; g < 18; ++g) {
      const ushort4 r4 = kr4[g];
      s += qv[g * 4 + 0] * bfu2f(r4.x) + qv[g * 4 + 1] * bfu2f(r4.y)
         + qv[g * 4 + 2] * bfu2f(r4.z) + qv[g * 4 + 3] * bfu2f(r4.w);
    }
    const float ma = (1.0f - mask[b * SEQ + j]) * -3.4028234663852886e38f;
    sc[j] = s * scale + ma;
  }
  __syncthreads();
  float mx = -1e30f;
  for (int j = tid; j < SEQ; j += 256) mx = fmaxf(mx, sc[j]);
  for (int off = 32; off; off >>= 1) mx = fmaxf(mx, __shfl_down(mx, off));
  if ((tid & 63) == 0) red[tid >> 6] = mx;
  __syncthreads();
  mx = fmaxf(fmaxf(red[0], red[1]), fmaxf(red[2], red[3]));
  float sm = 0.f;
  for (int j = tid; j < SEQ; j += 256) { float p = __expf(sc[j] - mx); sc[j] = p; sm += p; }
  for (int off = 32; off; off >>= 1) sm += __shfl_down(sm, off);
  if ((tid & 63) == 0) red[4 + (tid >> 6)] = sm;
  __syncthreads();
  sm = red[4] + red[5] + red[6] + red[7];
  if (tid < 216) {
    const int d = tid % HEADDIM, js = tid / HEADDIM;
    float o = 0.f;
    for (int j = js; j < SEQ; j += 3)
      o += sc[j] * bfu2f(Vb[((size_t)(b * SEQ + j)) * DMODEL + h * HEADDIM + d]);
    opart[js][d] = o;
  }
  __syncthreads();
  if (tid < HEADDIM)
    hp[b * DMODEL + h * HEADDIM + tid] =
        (opart[0][tid] + opart[1][tid] + opart[2][tid]) / sm;
}

// ---------------- split-K GEMV for tiny-M head GEMMs (f32 weights) -------
#define KSPLIT 16
#define KCMAX  272

__global__ __launch_bounds__(256) void gemv_splitk(
    const float* __restrict__ A, const float* __restrict__ W,
    float* __restrict__ part, int M, int N, int K)
{
  __shared__ float As[4 * KCMAX];
  const int tid = threadIdx.x;
  const int ks = blockIdx.y;
  const int kc = (K + KSPLIT - 1) / KSPLIT;
  const int k0 = ks * kc;
  const int len = min(K, k0 + kc) - k0;
  for (int i = tid; i < M * len; i += 256) {
    const int m = i / len, k = i - m * len;
    As[m * KCMAX + k] = A[(size_t)m * K + k0 + k];
  }
  __syncthreads();
  const int n = blockIdx.x * 256 + tid;
  if (n >= N) return;
  const float* wp = W + (size_t)k0 * N + n;
  if (M == 1) {
    float a0 = 0.f;
#pragma unroll 4
    for (int k = 0; k < len; ++k) a0 += As[k] * wp[(size_t)k * N];
    part[(size_t)ks * N + n] = a0;
  } else {
    float a0 = 0.f, a1 = 0.f, a2 = 0.f, a3 = 0.f;
#pragma unroll 4
    for (int k = 0; k < len; ++k) {
      const float w = wp[(size_t)k * N];
      a0 += As[0 * KCMAX + k] * w;
      a1 += As[1 * KCMAX + k] * w;
      a2 += As[2 * KCMAX + k] * w;
      a3 += As[3 * KCMAX + k] * w;
    }
    float* pb = part + (size_t)ks * 4 * N + n;
    pb[0 * N] = a0; pb[1 * N] = a1; pb[2 * N] = a2; pb[3 * N] = a3;
  }
}

__global__ __launch_bounds__(256) void gemv_reduce(
    const float* __restrict__ part, const float* __restrict__ bias,
    const float* __restrict__ R, float* __restrict__ C, int M, int N, int mode)
{
  const int n = blockIdx.x * 256 + threadIdx.x;
  const int m = blockIdx.y;
  if (n >= N) return;
  float s = 0.f;
#pragma unroll
  for (int ks = 0; ks < KSPLIT; ++ks) s += part[((size_t)ks * M + m) * N + n];
  s += bias[n];
  if (mode == 1) s += R[(size_t)m * N + n];
  else if (mode == 2) s = gelu_tanh(s);
  C[(size_t)m * N + n] = s;
}

// ---------------- host orchestration ----------------
extern "C" void kernel_launch(void* const* d_in, const int* in_sizes, int n_in,
                              void* d_out, int out_size, void* d_ws, size_t ws_size,
                              hipStream_t stream) {
  (void)in_sizes; (void)n_in; (void)out_size; (void)ws_size;
  const float* pixel   = (const float*)d_in[0];
  const float* amask   = (const float*)d_in[1];
  const int*   sshapes = (const int*)d_in[2];
  const float* patch_w = (const float*)d_in[3];
  const float* patch_b = (const float*)d_in[4];
  const float* pos_emb = (const float*)d_in[5];
  const float* ln1_w   = (const float*)d_in[6];
  const float* ln1_b   = (const float*)d_in[7];
  const float* qw      = (const float*)d_in[8];
  const float* qb      = (const float*)d_in[9];
  const float* kw      = (const float*)d_in[10];
  const float* kb      = (const float*)d_in[11];
  const float* vw      = (const float*)d_in[12];
  const float* vb      = (const float*)d_in[13];
  const float* ow      = (const float*)d_in[14];
  const float* ob      = (const float*)d_in[15];
  const float* ln2_w   = (const float*)d_in[16];
  const float* ln2_b   = (const float*)d_in[17];
  const float* fc1_w   = (const float*)d_in[18];
  const float* fc1_b   = (const float*)d_in[19];
  const float* fc2_w   = (const float*)d_in[20];
  const float* fc2_b   = (const float*)d_in[21];
  const float* postw   = (const float*)d_in[22];
  const float* postb   = (const float*)d_in[23];
  const float* probe   = (const float*)d_in[24];
  const float* h_qw    = (const float*)d_in[25];
  const float* h_qb    = (const float*)d_in[26];
  const float* h_kw    = (const float*)d_in[27];
  const float* h_kb    = (const float*)d_in[28];
  const float* h_vw    = (const float*)d_in[29];
  const float* h_vb    = (const float*)d_in[30];
  const float* h_ow    = (const float*)d_in[31];
  const float* h_ob    = (const float*)d_in[32];
  const float* h_ln_w  = (const float*)d_in[33];
  const float* h_ln_b  = (const float*)d_in[34];
  const float* h_fc1_w = (const float*)d_in[35];
  const float* h_fc1_b = (const float*)d_in[36];
  const float* h_fc2_w = (const float*)d_in[37];
  const float* h_fc2_b = (const float*)d_in[38];

  const size_t NTOK = (size_t)BATCH * SEQ;                 // 4096
  const size_t ACT  = NTOK * DMODEL;                       // 4.72M elems
  float* hbuf           = (float*)d_ws;                    // residual (f32)
  unsigned short* xa    = (unsigned short*)(hbuf + ACT);   // LN out (bf16)
  unsigned short* qkvb  = xa + ACT;                        // fused qkv (bf16)
  unsigned short* abuf  = qkvb + NTOK * 3456;              // attn out (bf16)
  unsigned short* tb    = qkvb;                            // fc1 out, aliases qkv+abuf
  unsigned short* pxb   = abuf;                            // pixel bf16, aliases abuf
  unsigned short* khb   = qkvb;                            // head K (bf16)
  unsigned short* vhb   = qkvb + ACT;                      // head V (bf16)
  unsigned short* wbufA = abuf + ACT;                      // weight scratch A
  unsigned short* wbufB = wbufA + (size_t)1152 * 4320;     // weight scratch B
  float* smal = (float*)(wbufB + (size_t)1152 * 4320);
  float* hqv  = smal;                                      // 1152
  float* hpb  = hqv + DMODEL;                              // 4x1152
  float* hp2  = hpb + BATCH * DMODEL;
  float* hpn  = hp2 + BATCH * DMODEL;
  float* htb  = hpn + BATCH * DMODEL;                      // 4x4304
  float* bqkv = htb + BATCH * FFDIM;                       // 3456 fused bias
  float* part = hbuf;                                      // splitk partials

  float* out_last   = (float*)d_out;
  float* out_pooled = out_last + ACT;

  const dim3 blk(256), tblk(32, 8);
  const dim3 gD(9, 32), gQKV(27, 32), gF(34, 32);

  // patch embedding (bf16 MFMA, K padded 588->608) + positional add
  cvt_pixel<<<dim3(3, 4096), blk, 0, stream>>>(pixel, pxb);
  transpose_cvt<<<dim3(36, 19), tblk, 0, stream>>>(patch_w, wbufA, 588, 1152, 608);
  gemm_bt<<<gD, blk, 0, stream>>>(pxb, wbufA, patch_b, nullptr, hbuf,
                                  (int)NTOK, 1152, 608, 1152, 1152, 0, 0);
  pos_add_kernel<<<(int)NTOK, 288, 0, stream>>>(pos_emb, sshapes, hbuf);

  for (int l = 0; l < NLAYERS; ++l) {
    const size_t wo = (size_t)l * DMODEL * DMODEL;
    const size_t fo = (size_t)l * DMODEL * FFDIM;
    const size_t bo = (size_t)l * DMODEL;
    const size_t fb = (size_t)l * FFDIM;
    // fused QKV weights -> W^T bf16, fused bias
    transpose_cvt<<<dim3(36, 36), tblk, 0, stream>>>(qw + wo, wbufA, 1152, 1152, 1152);
    transpose_cvt<<<dim3(36, 36), tblk, 0, stream>>>(kw + wo, wbufA + (size_t)1152 * 1152, 1152, 1152, 1152);
    transpose_cvt<<<dim3(36, 36), tblk, 0, stream>>>(vw + wo, wbufA + (size_t)2 * 1152 * 1152, 1152, 1152, 1152);
    concat3<<<5, blk, 0, stream>>>(qb + bo, kb + bo, vb + bo, bqkv, 1152);
    ln_kernel<<<(int)NTOK, blk, 0, stream>>>(hbuf, ln1_w + bo, ln1_b + bo, nullptr, xa);
    gemm_bt<<<gQKV, blk, 0, stream>>>(xa, wbufA, bqkv, nullptr, qkvb,
                                      (int)NTOK, 3456, 1152, 3456, 3456, 0, 1);
    attn_kernel<<<dim3(SEQ / 128, NHEADS, BATCH), 512, 0, stream>>>(qkvb, amask, abuf);
    transpose_cvt<<<dim3(36, 36), tblk, 0, stream>>>(ow + wo, wbufB, 1152, 1152, 1152);
    gemm_bt<<<gD, blk, 0, stream>>>(abuf, wbufB, ob + bo, hbuf, hbuf,
                                    (int)NTOK, 1152, 1152, 1152, 1152, 1, 0);
    ln_kernel<<<(int)NTOK, blk, 0, stream>>>(hbuf, ln2_w + bo, ln2_b + bo, nullptr, xa);
    transpose_cvt<<<dim3(135, 36), tblk, 0, stream>>>(fc1_w + fo, wbufA, 1152, 4304, 1152);
    gemm_bt<<<gF, blk, 0, stream>>>(xa, wbufA, fc1_b + fb, nullptr, tb,
                                    (int)NTOK, 4304, 1152, 4320, 4320, 2, 1);
    transpose_cvt<<<dim3(36, 135), tblk, 0, stream>>>(fc2_w + fo, wbufB, 4304, 1152, 4320);
    gemm_bt<<<gD, blk, 0, stream>>>(tb, wbufB, fc2_b + bo, hbuf, hbuf,
                                    (int)NTOK, 1152, 4320, 1152, 1152, 1, 0);
  }

  // post-LN: f32 -> out_last, bf16 -> xa (head GEMM input)
  ln_kernel<<<(int)NTOK, blk, 0, stream>>>(hbuf, postw, postb, out_last, xa);

  // head K/V projections (MFMA)
  transpose_cvt<<<dim3(36, 36), tblk, 0, stream>>>(h_kw, wbufA, 1152, 1152, 1152);
  gemm_bt<<<gD, blk, 0, stream>>>(xa, wbufA, h_kb, nullptr, khb,
                                  (int)NTOK, 1152, 1152, 1152, 1152, 0, 1);
  transpose_cvt<<<dim3(36, 36), tblk, 0, stream>>>(h_vw, wbufB, 1152, 1152, 1152);
  gemm_bt<<<gD, blk, 0, stream>>>(xa, wbufB, h_vb, nullptr, vhb,
                                  (int)NTOK, 1152, 1152, 1152, 1152, 0, 1);

  // head (split-K GEMVs on f32 weights; `part` aliases dead hbuf)
  const dim3 gv5(5, KSPLIT), gv17(17, KSPLIT);
  gemv_splitk<<<gv5, blk, 0, stream>>>(probe, h_qw, part, 1, DMODEL, DMODEL);
  gemv_reduce<<<dim3(5, 1), blk, 0, stream>>>(part, h_qb, nullptr, hqv, 1, DMODEL, 0);
  head_attn_kernel<<<dim3(NHEADS, BATCH), blk, 0, stream>>>(hqv, khb, vhb, amask, hpb);
  gemv_splitk<<<gv5, blk, 0, stream>>>(hpb, h_ow, part, BATCH, DMODEL, DMODEL);
  gemv_reduce<<<dim3(5, BATCH), blk, 0, stream>>>(part, h_ob, nullptr, hp2, BATCH, DMODEL, 0);
  ln_kernel<<<BATCH, blk, 0, stream>>>(hp2, h_ln_w, h_ln_b, hpn, nullptr);
  gemv_splitk<<<gv17, blk, 0, stream>>>(hpn, h_fc1_w, part, BATCH, FFDIM, DMODEL);
  gemv_reduce<<<dim3(17, BATCH), blk, 0, stream>>>(part, h_fc1_b, nullptr, htb, BATCH, FFDIM, 2);
  gemv_splitk<<<gv5, blk, 0, stream>>>(htb, h_fc2_w, part, BATCH, DMODEL, FFDIM);
  gemv_reduce<<<dim3(5, BATCH), blk, 0, stream>>>(part, h_fc2_b, hp2, out_pooled, BATCH, DMODEL, 1);
}

// Round 2
// 3340.770 us; speedup vs baseline: 1.7493x; 1.0734x over previous
//
#include <hip/hip_runtime.h>
#include <hip/hip_bf16.h>
#include <cstdint>
#include <cstddef>

// ---------------- problem constants ----------------
#define BATCH    4
#define SEQ      1024
#define DMODEL   1152
#define NHEADS   16
#define HEADDIM  72
#define FFDIM    4304
#define NLAYERS  6
#define PATCHIN  588
#define LN_EPS   1e-6f

typedef float f32x4 __attribute__((ext_vector_type(4)));
typedef __bf16 bf16x8 __attribute__((ext_vector_type(8)));
typedef short s16x8 __attribute__((ext_vector_type(8)));

__device__ __forceinline__ unsigned short f2bf(float f) {
  unsigned u = __builtin_bit_cast(unsigned, f);
  u = (u + 0x7fffu + ((u >> 16) & 1u)) >> 16;
  return (unsigned short)u;
}
__device__ __forceinline__ float bfu2f(unsigned short u) {
  return __builtin_bit_cast(float, (unsigned)u << 16);
}
__device__ __forceinline__ float gelu_tanh(float x) {
  const float c0 = 0.7978845608028654f, c1 = 0.044715f;
  return 0.5f * x * (1.0f + tanhf(c0 * (x + c1 * x * x * x)));
}
__device__ __forceinline__ void gload16(const unsigned short* g, unsigned short* l) {
  __builtin_amdgcn_global_load_lds(
      (__attribute__((address_space(1))) void*)g,
      (__attribute__((address_space(3))) void*)l, 16, 0, 0);
}

// ---------------- bf16 MFMA GEMM, B^T weights, global_load_lds staging ------
// C[M,N] = epi(A[M,K] @ BT[N,K]^T + bias). A,BT bf16 row-major, K%32==0.
// mode: 0=+bias, 1=+bias+Rres(f32), 2=gelu(+bias). outbf: 1 -> bf16 C.
// Double-buffered 2-phase K-loop (prefetch next tile during MFMA) +
// XCD-chunked column-grouped block swizzle for L2 panel reuse.
__global__ __launch_bounds__(256) void gemm_bt(
    const unsigned short* __restrict__ A, const unsigned short* __restrict__ BT,
    const float* __restrict__ bias, const float* __restrict__ Rres,
    void* __restrict__ Cout, int M, int N, int K, int ldc, int Nzero,
    int mode, int outbf)
{
  __shared__ __align__(16) unsigned short As[2][128 * 32];  // 2 x 8 KB
  __shared__ __align__(16) unsigned short Bs[2][128 * 32];
  const int tid = threadIdx.x;
  const int wave = tid >> 6, lane = tid & 63;
  const int lr = lane & 15, lq = lane >> 4;

  // ---- block swizzle: bijective XCD chunking (m204) + 8-wide column groups.
  // Consecutive ids on one XCD sweep 8 adjacent N-panels down M, so the
  // 8 B-panels (~2.3 MB) stay L2-resident and A-panels are row-shared.
  const int nbx = gridDim.x, nby = gridDim.y, nwg = nbx * nby;
  int id = blockIdx.y * nbx + blockIdx.x;
  {
    const int q = nwg >> 3, r = nwg & 7;
    const int xcd = id & 7, lid = id >> 3;
    id = (xcd < r ? xcd * (q + 1) : r * (q + 1) + (xcd - r) * q) + lid;
  }
  int bx, by;
  {
    const int W = 8;
    const int nfull = nbx / W;
    const int fullids = nfull * W * nby;
    if (id < fullids) {
      const int per = W * nby;
      const int g = id / per, rem = id % per;
      by = rem / W; bx = g * W + rem % W;
    } else {
      const int wl = nbx - nfull * W;
      const int d2 = id - fullids;
      by = d2 / wl; bx = nfull * W + d2 % wl;
    }
  }
  const int m0 = by * 128, n0 = bx * 128;
  const int wm = (wave & 1) * 64, wn = (wave >> 1) * 64;

  // staging map: slot s in {tid, tid+256}; row = s>>2, kchunk = s&3 (8 bf16).
  const int rowA = tid >> 2, kc = tid & 3;
  const unsigned short* gA0 = A + (size_t)(m0 + rowA) * K + kc * 8;
  const unsigned short* gA1 = gA0 + (size_t)64 * K;
  const int rB0 = min(n0 + rowA, N - 1);        // clamp tail (discarded cols)
  const int rB1 = min(n0 + rowA + 64, N - 1);
  const unsigned short* gB0 = BT + (size_t)rB0 * K + kc * 8;
  const unsigned short* gB1 = BT + (size_t)rB1 * K + kc * 8;

  f32x4 acc[4][4];
#pragma unroll
  for (int i = 0; i < 4; ++i)
#pragma unroll
    for (int j = 0; j < 4; ++j) acc[i][j] = (f32x4)(0.0f);

  const int nk = K >> 5;
  // prologue: stage tile 0 into buffer 0
  {
    unsigned short* la = &As[0][tid * 8];
    unsigned short* lb = &Bs[0][tid * 8];
    gload16(gA0, la);
    gload16(gA1, la + 256 * 8);
    gload16(gB0, lb);
    gload16(gB1, lb + 256 * 8);
  }
  __syncthreads();                       // buffer 0 ready

  for (int t = 0; t < nk; ++t) {
    const int cur = t & 1;
    if (t + 1 < nk) {                    // issue next-tile prefetch FIRST
      const int k0 = (t + 1) << 5;
      unsigned short* la = &As[cur ^ 1][tid * 8];
      unsigned short* lb = &Bs[cur ^ 1][tid * 8];
      gload16(gA0 + k0, la);
      gload16(gA1 + k0, la + 256 * 8);
      gload16(gB0 + k0, lb);
      gload16(gB1 + k0, lb + 256 * 8);
    }
    s16x8 af[4], bfr[4];
#pragma unroll
    for (int mi = 0; mi < 4; ++mi)
      af[mi] = *(const s16x8*)&As[cur][(wm + mi * 16 + lr) * 32 + lq * 8];
#pragma unroll
    for (int ni = 0; ni < 4; ++ni)
      bfr[ni] = *(const s16x8*)&Bs[cur][(wn + ni * 16 + lr) * 32 + lq * 8];
#pragma unroll
    for (int mi = 0; mi < 4; ++mi)
#pragma unroll
      for (int ni = 0; ni < 4; ++ni)
        acc[mi][ni] = __builtin_amdgcn_mfma_f32_16x16x32_bf16(
            __builtin_bit_cast(bf16x8, af[mi]),
            __builtin_bit_cast(bf16x8, bfr[ni]), acc[mi][ni], 0, 0, 0);
    // single drain point per K-step: vmcnt(0) (prefetch landed) +
    // lgkmcnt(0) + barrier (all waves done reading buf[cur] before overwrite)
    __syncthreads();
  }
  // epilogue: D[row=(lane>>4)*4+r][col=lane&15]  (verified layout)
  unsigned short* cb = (unsigned short*)Cout;
  float* cf = (float*)Cout;
#pragma unroll
  for (int ni = 0; ni < 4; ++ni) {
    const int col = n0 + wn + ni * 16 + lr;
    if (col < N) {
      const float bv = bias[col];
#pragma unroll
      for (int mi = 0; mi < 4; ++mi)
#pragma unroll
        for (int r = 0; r < 4; ++r) {
          const int row = m0 + wm + mi * 16 + lq * 4 + r;
          float v = acc[mi][ni][r] + bv;
          if (mode == 1) v += Rres[(size_t)row * ldc + col];
          else if (mode == 2) v = gelu_tanh(v);
          if (outbf) cb[(size_t)row * ldc + col] = f2bf(v);
          else cf[(size_t)row * ldc + col] = v;
        }
    } else if (col < Nzero) {   // zero-fill K-padding columns (bf16 out only)
#pragma unroll
      for (int mi = 0; mi < 4; ++mi)
#pragma unroll
        for (int r = 0; r < 4; ++r) {
          const int row = m0 + wm + mi * 16 + lq * 4 + r;
          cb[(size_t)row * ldc + col] = 0;
        }
    }
  }
}

// ---------------- weight transpose + fp32->bf16 convert ----------------
// W[K][N] f32  ->  WT[N][KP] bf16, zero-padded for k in [K,KP). KP%32==0.
__global__ __launch_bounds__(256) void transpose_cvt(
    const float* __restrict__ W, unsigned short* __restrict__ WT,
    int K, int N, int KP)
{
  __shared__ float t[32][33];
  const int n0 = blockIdx.x * 32, k0 = blockIdx.y * 32;
  const int tx = threadIdx.x, ty = threadIdx.y;
#pragma unroll
  for (int i = 0; i < 32; i += 8) {
    const int k = k0 + ty + i, n = n0 + tx;
    t[ty + i][tx] = (k < K && n < N) ? W[(size_t)k * N + n] : 0.f;
  }
  __syncthreads();
#pragma unroll
  for (int i = 0; i < 32; i += 8) {
    const int n = n0 + ty + i, k = k0 + tx;
    if (n < N) WT[(size_t)n * KP + k] = f2bf(t[tx][ty + i]);
  }
}

// ---------------- pixel f32 -> bf16 with K-pad 588->608 ----------------
__global__ __launch_bounds__(256) void cvt_pixel(
    const float* __restrict__ P, unsigned short* __restrict__ Pb)
{
  const int col = blockIdx.x * 256 + threadIdx.x;
  const int row = blockIdx.y;
  if (col < 608) {
    const float v = (col < PATCHIN) ? P[(size_t)row * PATCHIN + col] : 0.f;
    Pb[(size_t)row * 608 + col] = f2bf(v);
  }
}

__global__ __launch_bounds__(256) void concat3(
    const float* __restrict__ a, const float* __restrict__ b,
    const float* __restrict__ c, float* __restrict__ o, int n)
{
  const int i = blockIdx.x * 256 + threadIdx.x;
  if (i < n) { o[i] = a[i]; o[n + i] = b[i]; o[2 * n + i] = c[i]; }
}

// ---------------- LayerNorm rows of 1152: f32 in, f32/bf16 out ----------
__global__ __launch_bounds__(256) void ln_kernel(
    const float* __restrict__ in, const float* __restrict__ w,
    const float* __restrict__ b, float* __restrict__ of32,
    unsigned short* __restrict__ ob16)
{
  const int row = blockIdx.x, tid = threadIdx.x;
  __shared__ float red[8];
  const float4* x4 = (const float4*)(in + (size_t)row * DMODEL);
  const bool has2 = tid < 32;                 // 288 float4 = 256 + 32
  float4 v0 = x4[tid];
  float4 v1 = has2 ? x4[256 + tid] : make_float4(0.f, 0.f, 0.f, 0.f);
  float s = v0.x + v0.y + v0.z + v0.w + v1.x + v1.y + v1.z + v1.w;
  for (int off = 32; off; off >>= 1) s += __shfl_down(s, off);
  if ((tid & 63) == 0) red[tid >> 6] = s;
  __syncthreads();
  const float mean = (red[0] + red[1] + red[2] + red[3]) * (1.0f / DMODEL);
  float vs = (v0.x - mean) * (v0.x - mean) + (v0.y - mean) * (v0.y - mean)
           + (v0.z - mean) * (v0.z - mean) + (v0.w - mean) * (v0.w - mean);
  if (has2)
    vs += (v1.x - mean) * (v1.x - mean) + (v1.y - mean) * (v1.y - mean)
        + (v1.z - mean) * (v1.z - mean) + (v1.w - mean) * (v1.w - mean);
  for (int off = 32; off; off >>= 1) vs += __shfl_down(vs, off);
  if ((tid & 63) == 0) red[4 + (tid >> 6)] = vs;
  __syncthreads();
  const float var = (red[4] + red[5] + red[6] + red[7]) * (1.0f / DMODEL);
  const float rstd = rsqrtf(var + LN_EPS);
  const float4* w4 = (const float4*)w;
  const float4* b4 = (const float4*)b;
  {
    float4 ww = w4[tid], bb = b4[tid], o;
    o.x = (v0.x - mean) * rstd * ww.x + bb.x;
    o.y = (v0.y - mean) * rstd * ww.y + bb.y;
    o.z = (v0.z - mean) * rstd * ww.z + bb.z;
    o.w = (v0.w - mean) * rstd * ww.w + bb.w;
    if (of32) ((float4*)(of32 + (size_t)row * DMODEL))[tid] = o;
    if (ob16) {
      ushort4 u; u.x = f2bf(o.x); u.y = f2bf(o.y); u.z = f2bf(o.z); u.w = f2bf(o.w);
      ((ushort4*)(ob16 + (size_t)row * DMODEL))[tid] = u;
    }
  }
  if (has2) {
    float4 ww = w4[256 + tid], bb = b4[256 + tid], o;
    o.x = (v1.x - mean) * rstd * ww.x + bb.x;
    o.y = (v1.y - mean) * rstd * ww.y + bb.y;
    o.z = (v1.z - mean) * rstd * ww.z + bb.z;
    o.w = (v1.w - mean) * rstd * ww.w + bb.w;
    if (of32) ((float4*)(of32 + (size_t)row * DMODEL))[256 + tid] = o;
    if (ob16) {
      ushort4 u; u.x = f2bf(o.x); u.y = f2bf(o.y); u.z = f2bf(o.z); u.w = f2bf(o.w);
      ((ushort4*)(ob16 + (size_t)row * DMODEL))[256 + tid] = u;
    }
  }
}

// ---------------- position-embedding bilinear resize + add (f32) --------
__global__ __launch_bounds__(288) void pos_add_kernel(
    const float* __restrict__ pos, const int* __restrict__ ssp,
    float* __restrict__ hbuf)
{
  const int bs = blockIdx.x;
  const int b = bs >> 10, s = bs & (SEQ - 1);
  int hs, wd;
  if (ssp[1] == 0 && ssp[3] == 0) { hs = ssp[b * 4]; wd = ssp[b * 4 + 2]; }
  else { hs = ssp[b * 2]; wd = ssp[b * 2 + 1]; }
  int r = 0, c = 0;
  if (s < hs * wd) { r = s / wd; c = s % wd; }
  const float fy = (r + 0.5f) * (16.0f / hs) - 0.5f;
  const float fx = (c + 0.5f) * (16.0f / wd) - 0.5f;
  const float y0f = floorf(fy), x0f = floorf(fx);
  const float ty = fy - y0f, tx = fx - x0f;
  const int y0 = (int)y0f, x0 = (int)x0f;
  const int y0c = min(max(y0, 0), 15), y1c = min(max(y0 + 1, 0), 15);
  const int x0c = min(max(x0, 0), 15), x1c = min(max(x0 + 1, 0), 15);
  const float w00 = (1.f - ty) * (1.f - tx), w01 = (1.f - ty) * tx;
  const float w10 = ty * (1.f - tx), w11 = ty * tx;
  const float* p00 = pos + (size_t)(y0c * 16 + x0c) * DMODEL;
  const float* p01 = pos + (size_t)(y0c * 16 + x1c) * DMODEL;
  const float* p10 = pos + (size_t)(y1c * 16 + x0c) * DMODEL;
  const float* p11 = pos + (size_t)(y1c * 16 + x1c) * DMODEL;
  float* hrow = hbuf + (size_t)bs * DMODEL;
  const int d0 = threadIdx.x * 4;
#pragma unroll
  for (int i = 0; i < 4; ++i) {
    const int d = d0 + i;
    hrow[d] += w00 * p00[d] + w01 * p01[d] + w10 * p10[d] + w11 * p11[d];
  }
}

// ---------------- MFMA flash attention, bf16 fused-QKV in, bf16 out ------
// grid (SEQ/128, NHEADS, BATCH), 512 threads = 8 waves; wave w owns 16 q-rows.
// Fragment layout mirrors gemm_bt (verified): A row=lane&15, k=(lane>>4)*8;
// C row=(lane>>4)*4+r, col=lane&15.
__global__ __launch_bounds__(512, 4) void attn_kernel(
    const unsigned short* __restrict__ QKV, const float* __restrict__ mask,
    unsigned short* __restrict__ Oa)
{
  // strides chosen so all ds_read_b128 fragment reads hit the 8/bank floor:
  // Qs/Ks stride 96 elems (48 dw = 16 mod 32), VT/Ps stride 72 (36 dw = 4 mod 32)
  __shared__ __align__(16) unsigned short Qs[128][96];   // 24.0 KB, d padded 72->96
  __shared__ __align__(16) unsigned short Ks[64][96];    // 12.0 KB
  __shared__ __align__(16) unsigned short VT[80][72];    // 11.25 KB, V transposed [d][j]
  __shared__ __align__(16) unsigned short Ps[128][72];   // 18.0 KB, P bf16 (cols 0..63 used)
  __shared__ float madd_s[64];
  const int tid = threadIdx.x;
  const int wave = tid >> 6, lane = tid & 63;
  const int lr = lane & 15, lq = lane >> 4;
  const int q0 = blockIdx.x * 128, h = blockIdx.y, b = blockIdx.z;
  const int wq0 = wave * 16;
  const float scale = 0.11785113019775793f;     // 1/sqrt(72)

  // zero pads once: Qs/Ks cols [72,96), VT rows [72,80)
  {
    const s16x8 z = {0, 0, 0, 0, 0, 0, 0, 0};
    for (int idx = tid; idx < 128 * 3; idx += 512) {
      const int row = idx / 3, g = idx % 3;
      *(s16x8*)&Qs[row][72 + g * 8] = z;
    }
    if (tid < 64 * 3) {
      const int row = tid / 3, g = tid % 3;
      *(s16x8*)&Ks[row][72 + g * 8] = z;
    }
    if (tid < 72) {
      const int row = 72 + tid / 9, g = tid % 9;
      *(s16x8*)&VT[row][g * 8] = z;
    }
  }
  // load Q tile once (bf16, 16B per item)
  for (int idx = tid; idx < 128 * 9; idx += 512) {
    const int qi = idx / 9, g = idx % 9;
    *(s16x8*)&Qs[qi][g * 8] = *(const s16x8*)(
        QKV + ((size_t)(b * SEQ + q0 + qi)) * 3456 + h * HEADDIM + g * 8);
  }

  f32x4 acc_o[5];
#pragma unroll
  for (int i = 0; i < 5; ++i) acc_o[i] = (f32x4)(0.0f);
  float m_old[4], lden[4];
#pragma unroll
  for (int r = 0; r < 4; ++r) { m_old[r] = -1e30f; lden[r] = 0.f; }

  for (int kt = 0; kt < SEQ / 64; ++kt) {
    const int k0 = kt * 64;
    __syncthreads();        // prev iter's Ks/VT consumers done (also Q ready)
    for (int idx = tid; idx < 64 * 9; idx += 512) {
      const int j = idx / 9, g = idx % 9;
      const size_t base = ((size_t)(b * SEQ + k0 + j)) * 3456 + h * HEADDIM + g * 8;
      const s16x8 kr = *(const s16x8*)(QKV + base + 1152);
      const s16x8 vr = *(const s16x8*)(QKV + base + 2304);
      *(s16x8*)&Ks[j][g * 8] = kr;
#pragma unroll
      for (int i = 0; i < 8; ++i) VT[g * 8 + i][j] = (unsigned short)vr[i];
    }
    if (tid < 64)
      madd_s[tid] = (1.0f - mask[b * SEQ + k0 + tid]) * -3.4028234663852886e38f;
    __syncthreads();

    // ---- QK^T: S[16 q][64 k] per wave, K-dim 96 (3 chunks) -> 12 MFMAs ----
    f32x4 acc[4];
#pragma unroll
    for (int ni = 0; ni < 4; ++ni) acc[ni] = (f32x4)(0.0f);
    s16x8 aq[3];
#pragma unroll
    for (int c = 0; c < 3; ++c)
      aq[c] = *(const s16x8*)&Qs[wq0 + lr][c * 32 + lq * 8];
#pragma unroll
    for (int ni = 0; ni < 4; ++ni)
#pragma unroll
      for (int c = 0; c < 3; ++c) {
        const s16x8 bk = *(const s16x8*)&Ks[ni * 16 + lr][c * 32 + lq * 8];
        acc[ni] = __builtin_amdgcn_mfma_f32_16x16x32_bf16(
            __builtin_bit_cast(bf16x8, aq[c]), __builtin_bit_cast(bf16x8, bk),
            acc[ni], 0, 0, 0);
      }

    // ---- online softmax: 16-lane group owns rows wq0+lq*4+r, col=lr ----
    float sv[4][4];
#pragma unroll
    for (int ni = 0; ni < 4; ++ni) {
      const float ma = madd_s[ni * 16 + lr];
#pragma unroll
      for (int r = 0; r < 4; ++r) sv[ni][r] = acc[ni][r] * scale + ma;
    }
    float alpha[4];
#pragma unroll
    for (int r = 0; r < 4; ++r) {
      float tm = fmaxf(fmaxf(sv[0][r], sv[1][r]), fmaxf(sv[2][r], sv[3][r]));
      tm = fmaxf(tm, __shfl_xor(tm, 1));
      tm = fmaxf(tm, __shfl_xor(tm, 2));
      tm = fmaxf(tm, __shfl_xor(tm, 4));
      tm = fmaxf(tm, __shfl_xor(tm, 8));
      const float mn = fmaxf(m_old[r], tm);
      alpha[r] = __expf(m_old[r] - mn);
      m_old[r] = mn;
    }
    float lsum[4] = {0.f, 0.f, 0.f, 0.f};
#pragma unroll
    for (int ni = 0; ni < 4; ++ni)
#pragma unroll
      for (int r = 0; r < 4; ++r) {
        const float p = __expf(sv[ni][r] - m_old[r]);
        Ps[wq0 + lq * 4 + r][ni * 16 + lr] = f2bf(p);
        lsum[r] += p;
      }
#pragma unroll
    for (int r = 0; r < 4; ++r) {
      float ls = lsum[r];
      ls += __shfl_xor(ls, 1);
      ls += __shfl_xor(ls, 2);
      ls += __shfl_xor(ls, 4);
      ls += __shfl_xor(ls, 8);
      lden[r] = lden[r] * alpha[r] + ls;
    }

    // ---- PV: O[16 q][80 d] += P[16][64] @ V[64][80], 10 MFMAs ----
    // Ps written/read by the SAME wave -> in-order LDS, no barrier needed.
#pragma unroll
    for (int ni = 0; ni < 5; ++ni)
#pragma unroll
      for (int r = 0; r < 4; ++r) acc_o[ni][r] *= alpha[r];
    s16x8 pa[2];
    pa[0] = *(const s16x8*)&Ps[wq0 + lr][lq * 8];
    pa[1] = *(const s16x8*)&Ps[wq0 + lr][32 + lq * 8];
#pragma unroll
    for (int ni = 0; ni < 5; ++ni)
#pragma unroll
      for (int c = 0; c < 2; ++c) {
        const s16x8 bv = *(const s16x8*)&VT[ni * 16 + lr][c * 32 + lq * 8];
        acc_o[ni] = __builtin_amdgcn_mfma_f32_16x16x32_bf16(
            __builtin_bit_cast(bf16x8, pa[c]), __builtin_bit_cast(bf16x8, bv),
            acc_o[ni], 0, 0, 0);
      }
  }

  // epilogue: O row = q0+wq0+lq*4+r, col = ni*16+lr (d<72)
  float rl[4];
#pragma unroll
  for (int r = 0; r < 4; ++r) rl[r] = 1.0f / lden[r];
#pragma unroll
  for (int ni = 0; ni < 5; ++ni) {
    const int col = ni * 16 + lr;
    if (col < HEADDIM) {
#pragma unroll
      for (int r = 0; r < 4; ++r) {
        const int row = q0 + wq0 + lq * 4 + r;
        Oa[((size_t)(b * SEQ + row)) * DMODEL + h * HEADDIM + col] =
            f2bf(acc_o[ni][r] * rl[r]);
      }
    }
  }
}

// ---------------- head attention-pooling (bf16 K/V) ----------------
__global__ __launch_bounds__(256) void head_attn_kernel(
    const float* __restrict__ hq, const unsigned short* __restrict__ Kb,
    const unsigned short* __restrict__ Vb, const float* __restrict__ mask,
    float* __restrict__ hp)
{
  __shared__ float sc[SEQ];
  __shared__ float red[8];
  __shared__ float qv[HEADDIM];
  __shared__ float opart[3][HEADDIM];
  const int h = blockIdx.x, b = blockIdx.y, tid = threadIdx.x;
  const float scale = 0.11785113019775793f;
  if (tid < HEADDIM) qv[tid] = hq[h * HEADDIM + tid];
  __syncthreads();
  for (int j = tid; j < SEQ; j += 256) {
    const ushort4* kr4 = (const ushort4*)(
        Kb + ((size_t)(b * SEQ + j)) * DMODEL + h * HEADDIM);
    float s = 0.f;
#pragma unroll
    for (int g = 0; g < 18; ++g) {
      const ushort4 r4 = kr4[g];
      s += qv[g * 4 + 0] * bfu2f(r4.x) + qv[g * 4 + 1] * bfu2f(r4.y)
         + qv[g * 4 + 2] * bfu2f(r4.z) + qv[g * 4 + 3] * bfu2f(r4.w);
    }
    const float ma = (1.0f - mask[b * SEQ + j]) * -3.4028234663852886e38f;
    sc[j] = s * scale + ma;
  }
  __syncthreads();
  float mx = -1e30f;
  for (int j = tid; j < SEQ; j += 256) mx = fmaxf(mx, sc[j]);
  for (int off = 32; off; off >>= 1) mx = fmaxf(mx, __shfl_down(mx, off));
  if ((tid & 63) == 0) red[tid >> 6] = mx;
  __syncthreads();
  mx = fmaxf(fmaxf(red[0], red[1]), fmaxf(red[2], red[3]));
  float sm = 0.f;
  for (int j = tid; j < SEQ; j += 256) { float p = __expf(sc[j] - mx); sc[j] = p; sm += p; }
  for (int off = 32; off; off >>= 1) sm += __shfl_down(sm, off);
  if ((tid & 63) == 0) red[4 + (tid >> 6)] = sm;
  __syncthreads();
  sm = red[4] + red[5] + red[6] + red[7];
  if (tid < 216) {
    const int d = tid % HEADDIM, js = tid / HEADDIM;
    float o = 0.f;
    for (int j = js; j < SEQ; j += 3)
      o += sc[j] * bfu2f(Vb[((size_t)(b * SEQ + j)) * DMODEL + h * HEADDIM + d]);
    opart[js][d] = o;
  }
  __syncthreads();
  if (tid < HEADDIM)
    hp[b * DMODEL + h * HEADDIM + tid] =
        (opart[0][tid] + opart[1][tid] + opart[2][tid]) / sm;
}

// ---------------- split-K GEMV for tiny-M head GEMMs (f32 weights) -------
#define KSPLIT 16
#define KCMAX  272

__global__ __launch_bounds__(256) void gemv_splitk(
    const float* __restrict__ A, const float* __restrict__ W,
    float* __restrict__ part, int M, int N, int K)
{
  __shared__ float As[4 * KCMAX];
  const int tid = threadIdx.x;
  const int ks = blockIdx.y;
  const int kc = (K + KSPLIT - 1) / KSPLIT;
  const int k0 = ks * kc;
  const int len = min(K, k0 + kc) - k0;
  for (int i = tid; i < M * len; i += 256) {
    const int m = i / len, k = i - m * len;
    As[m * KCMAX + k] = A[(size_t)m * K + k0 + k];
  }
  __syncthreads();
  const int n = blockIdx.x * 256 + tid;
  if (n >= N) return;
  const float* wp = W + (size_t)k0 * N + n;
  if (M == 1) {
    float a0 = 0.f;
#pragma unroll 4
    for (int k = 0; k < len; ++k) a0 += As[k] * wp[(size_t)k * N];
    part[(size_t)ks * N + n] = a0;
  } else {
    float a0 = 0.f, a1 = 0.f, a2 = 0.f, a3 = 0.f;
#pragma unroll 4
    for (int k = 0; k < len; ++k) {
      const float w = wp[(size_t)k * N];
      a0 += As[0 * KCMAX + k] * w;
      a1 += As[1 * KCMAX + k] * w;
      a2 += As[2 * KCMAX + k] * w;
      a3 += As[3 * KCMAX + k] * w;
    }
    float* pb = part + (size_t)ks * 4 * N + n;
    pb[0 * N] = a0; pb[1 * N] = a1; pb[2 * N] = a2; pb[3 * N] = a3;
  }
}

__global__ __launch_bounds__(256) void gemv_reduce(
    const float* __restrict__ part, const float* __restrict__ bias,
    const float* __restrict__ R, float* __restrict__ C, int M, int N, int mode)
{
  const int n = blockIdx.x * 256 + threadIdx.x;
  const int m = blockIdx.y;
  if (n >= N) return;
  float s = 0.f;
#pragma unroll
  for (int ks = 0; ks < KSPLIT; ++ks) s += part[((size_t)ks * M + m) * N + n];
  s += bias[n];
  if (mode == 1) s += R[(size_t)m * N + n];
  else if (mode == 2) s = gelu_tanh(s);
  C[(size_t)m * N + n] = s;
}

// ---------------- host orchestration ----------------
extern "C" void kernel_launch(void* const* d_in, const int* in_sizes, int n_in,
                              void* d_out, int out_size, void* d_ws, size_t ws_size,
                              hipStream_t stream) {
  (void)in_sizes; (void)n_in; (void)out_size; (void)ws_size;
  const float* pixel   = (const float*)d_in[0];
  const float* amask   = (const float*)d_in[1];
  const int*   sshapes = (const int*)d_in[2];
  const float* patch_w = (const float*)d_in[3];
  const float* patch_b = (const float*)d_in[4];
  const float* pos_emb = (const float*)d_in[5];
  const float* ln1_w   = (const float*)d_in[6];
  const float* ln1_b   = (const float*)d_in[7];
  const float* qw      = (const float*)d_in[8];
  const float* qb      = (const float*)d_in[9];
  const float* kw      = (const float*)d_in[10];
  const float* kb      = (const float*)d_in[11];
  const float* vw      = (const float*)d_in[12];
  const float* vb      = (const float*)d_in[13];
  const float* ow      = (const float*)d_in[14];
  const float* ob      = (const float*)d_in[15];
  const float* ln2_w   = (const float*)d_in[16];
  const float* ln2_b   = (const float*)d_in[17];
  const float* fc1_w   = (const float*)d_in[18];
  const float* fc1_b   = (const float*)d_in[19];
  const float* fc2_w   = (const float*)d_in[20];
  const float* fc2_b   = (const float*)d_in[21];
  const float* postw   = (const float*)d_in[22];
  const float* postb   = (const float*)d_in[23];
  const float* probe   = (const float*)d_in[24];
  const float* h_qw    = (const float*)d_in[25];
  const float* h_qb    = (const float*)d_in[26];
  const float* h_kw    = (const float*)d_in[27];
  const float* h_kb    = (const float*)d_in[28];
  const float* h_vw    = (const float*)d_in[29];
  const float* h_vb    = (const float*)d_in[30];
  const float* h_ow    = (const float*)d_in[31];
  const float* h_ob    = (const float*)d_in[32];
  const float* h_ln_w  = (const float*)d_in[33];
  const float* h_ln_b  = (const float*)d_in[34];
  const float* h_fc1_w = (const float*)d_in[35];
  const float* h_fc1_b = (const float*)d_in[36];
  const float* h_fc2_w = (const float*)d_in[37];
  const float* h_fc2_b = (const float*)d_in[38];

  const size_t NTOK = (size_t)BATCH * SEQ;                 // 4096
  const size_t ACT  = NTOK * DMODEL;                       // 4.72M elems
  float* hbuf           = (float*)d_ws;                    // residual (f32)
  unsigned short* xa    = (unsigned short*)(hbuf + ACT);   // LN out (bf16)
  unsigned short* qkvb  = xa + ACT;                        // fused qkv (bf16)
  unsigned short* abuf  = qkvb + NTOK * 3456;              // attn out (bf16)
  unsigned short* tb    = qkvb;                            // fc1 out, aliases qkv+abuf
  unsigned short* pxb   = abuf;                            // pixel bf16, aliases abuf
  unsigned short* khb   = qkvb;                            // head K (bf16)
  unsigned short* vhb   = qkvb + ACT;                      // head V (bf16)
  unsigned short* wbufA = abuf + ACT;                      // weight scratch A
  unsigned short* wbufB = wbufA + (size_t)1152 * 4320;     // weight scratch B
  float* smal = (float*)(wbufB + (size_t)1152 * 4320);
  float* hqv  = smal;                                      // 1152
  float* hpb  = hqv + DMODEL;                              // 4x1152
  float* hp2  = hpb + BATCH * DMODEL;
  float* hpn  = hp2 + BATCH * DMODEL;
  float* htb  = hpn + BATCH * DMODEL;                      // 4x4304
  float* bqkv = htb + BATCH * FFDIM;                       // 3456 fused bias
  float* part = hbuf;                                      // splitk partials

  float* out_last   = (float*)d_out;
  float* out_pooled = out_last + ACT;

  const dim3 blk(256), tblk(32, 8);
  const dim3 gD(9, 32), gQKV(27, 32), gF(34, 32);

  // patch embedding (bf16 MFMA, K padded 588->608) + positional add
  cvt_pixel<<<dim3(3, 4096), blk, 0, stream>>>(pixel, pxb);
  transpose_cvt<<<dim3(36, 19), tblk, 0, stream>>>(patch_w, wbufA, 588, 1152, 608);
  gemm_bt<<<gD, blk, 0, stream>>>(pxb, wbufA, patch_b, nullptr, hbuf,
                                  (int)NTOK, 1152, 608, 1152, 1152, 0, 0);
  pos_add_kernel<<<(int)NTOK, 288, 0, stream>>>(pos_emb, sshapes, hbuf);

  for (int l = 0; l < NLAYERS; ++l) {
    const size_t wo = (size_t)l * DMODEL * DMODEL;
    const size_t fo = (size_t)l * DMODEL * FFDIM;
    const size_t bo = (size_t)l * DMODEL;
    const size_t fb = (size_t)l * FFDIM;
    // fused QKV weights -> W^T bf16, fused bias
    transpose_cvt<<<dim3(36, 36), tblk, 0, stream>>>(qw + wo, wbufA, 1152, 1152, 1152);
    transpose_cvt<<<dim3(36, 36), tblk, 0, stream>>>(kw + wo, wbufA + (size_t)1152 * 1152, 1152, 1152, 1152);
    transpose_cvt<<<dim3(36, 36), tblk, 0, stream>>>(vw + wo, wbufA + (size_t)2 * 1152 * 1152, 1152, 1152, 1152);
    concat3<<<5, blk, 0, stream>>>(qb + bo, kb + bo, vb + bo, bqkv, 1152);
    ln_kernel<<<(int)NTOK, blk, 0, stream>>>(hbuf, ln1_w + bo, ln1_b + bo, nullptr, xa);
    gemm_bt<<<gQKV, blk, 0, stream>>>(xa, wbufA, bqkv, nullptr, qkvb,
                                      (int)NTOK, 3456, 1152, 3456, 3456, 0, 1);
    attn_kernel<<<dim3(SEQ / 128, NHEADS, BATCH), 512, 0, stream>>>(qkvb, amask, abuf);
    transpose_cvt<<<dim3(36, 36), tblk, 0, stream>>>(ow + wo, wbufB, 1152, 1152, 1152);
    gemm_bt<<<gD, blk, 0, stream>>>(abuf, wbufB, ob + bo, hbuf, hbuf,
                                    (int)NTOK, 1152, 1152, 1152, 1152, 1, 0);
    ln_kernel<<<(int)NTOK, blk, 0, stream>>>(hbuf, ln2_w + bo, ln2_b + bo, nullptr, xa);
    transpose_cvt<<<dim3(135, 36), tblk, 0, stream>>>(fc1_w + fo, wbufA, 1152, 4304, 1152);
    gemm_bt<<<gF, blk, 0, stream>>>(xa, wbufA, fc1_b + fb, nullptr, tb,
                                    (int)NTOK, 4304, 1152, 4320, 4320, 2, 1);
    transpose_cvt<<<dim3(36, 135), tblk, 0, stream>>>(fc2_w + fo, wbufB, 4304, 1152, 4320);
    gemm_bt<<<gD, blk, 0, stream>>>(tb, wbufB, fc2_b + bo, hbuf, hbuf,
                                    (int)NTOK, 1152, 4320, 1152, 1152, 1, 0);
  }

  // post-LN: f32 -> out_last, bf16 -> xa (head GEMM input)
  ln_kernel<<<(int)NTOK, blk, 0, stream>>>(hbuf, postw, postb, out_last, xa);

  // head K/V projections (MFMA)
  transpose_cvt<<<dim3(36, 36), tblk, 0, stream>>>(h_kw, wbufA, 1152, 1152, 1152);
  gemm_bt<<<gD, blk, 0, stream>>>(xa, wbufA, h_kb, nullptr, khb,
                                  (int)NTOK, 1152, 1152, 1152, 1152, 0, 1);
  transpose_cvt<<<dim3(36, 36), tblk, 0, stream>>>(h_vw, wbufB, 1152, 1152, 1152);
  gemm_bt<<<gD, blk, 0, stream>>>(xa, wbufB, h_vb, nullptr, vhb,
                                  (int)NTOK, 1152, 1152, 1152, 1152, 0, 1);

  // head (split-K GEMVs on f32 weights; `part` aliases dead hbuf)
  const dim3 gv5(5, KSPLIT), gv17(17, KSPLIT);
  gemv_splitk<<<gv5, blk, 0, stream>>>(probe, h_qw, part, 1, DMODEL, DMODEL);
  gemv_reduce<<<dim3(5, 1), blk, 0, stream>>>(part, h_qb, nullptr, hqv, 1, DMODEL, 0);
  head_attn_kernel<<<dim3(NHEADS, BATCH), blk, 0, stream>>>(hqv, khb, vhb, amask, hpb);
  gemv_splitk<<<gv5, blk, 0, stream>>>(hpb, h_ow, part, BATCH, DMODEL, DMODEL);
  gemv_reduce<<<dim3(5, BATCH), blk, 0, stream>>>(part, h_ob, nullptr, hp2, BATCH, DMODEL, 0);
  ln_kernel<<<BATCH, blk, 0, stream>>>(hp2, h_ln_w, h_ln_b, hpn, nullptr);
  gemv_splitk<<<gv17, blk, 0, stream>>>(hpn, h_fc1_w, part, BATCH, FFDIM, DMODEL);
  gemv_reduce<<<dim3(17, BATCH), blk, 0, stream>>>(part, h_fc1_b, nullptr, htb, BATCH, FFDIM, 2);
  gemv_splitk<<<gv5, blk, 0, stream>>>(htb, h_fc2_w, part, BATCH, DMODEL, FFDIM);
  gemv_reduce<<<dim3(5, BATCH), blk, 0, stream>>>(part, h_fc2_b, hp2, out_pooled, BATCH, DMODEL, 1);
}